// Round 14
// baseline (219.474 us; speedup 1.0000x reference)
//
#include <hip/hip_runtime.h>
#include <hip/hip_bf16.h>

typedef __bf16 bf16;
typedef __bf16 bf16x8 __attribute__((ext_vector_type(8)));
typedef __bf16 bf16x4 __attribute__((ext_vector_type(4)));
typedef float  f32x4  __attribute__((ext_vector_type(4)));

#define GLD_LDS(g, l)                                                        \
  __builtin_amdgcn_global_load_lds(                                          \
      (const __attribute__((address_space(1))) void*)(g),                    \
      (__attribute__((address_space(3))) void*)(l), 16, 0, 0)

#define SB()    __builtin_amdgcn_s_barrier()
#define WVM(n)  asm volatile("s_waitcnt vmcnt(" #n ")" ::: "memory")
#define PRIO1() __builtin_amdgcn_s_setprio(1)
#define PRIO0() __builtin_amdgcn_s_setprio(0)

// ---------------------------------------------------------------------------
// gemm128k v2: R13 structure (128x128 tile, BK=64 in kk-halves, 8 waves
// 4Mx2N, LDS 64K => 2 blocks/CU) with R8's MEASURED-conflict-free
// paired-row LDS layout (R13's ad-hoc 64B-row swizzle hit 2.5e7 conflicts).
// Layout per 8KB kk-half: 64 lines x 128B; line l = rows {2l, 2l+1} as 8
// granules of 16B; granule g of line l holds (row 2l+h, k-chunk q) with
// h*4+q = g ^ (l&7).  [R8-verified: 0 bank conflicts, absmax 0.5]
//  - staging: 1 gld_lds issue per kk-half (512 thr x 16B, LINEAR dest);
//    thread t sources row 2*(t>>3)+ht, chunk qt, where gsw=(t&7)^((t>>3)&7),
//    ht=gsw>>2, qt=gsw&3 (rule #21: source pre-applies the involution).
//  - reads: laneb = (fr>>1)*128 + (((fr&1)*4+fq)^((fr>>1)&7))*16;
//    A frag m_: wm*2048 + m_*1024 + laneb (+kk*8192+p*16384);
//    B frag n_: 32768 + wn*4096 + n_*1024 + laneb (lane-constant since
//    m_*8 and n_*8 are 0 mod 8 in the line index).
// Schedule per K-tile (unchanged R13, 2 barriers, counted vmcnt):
//   [rd kk0 af+bg0][stg A.kk0(T+1)] MM0 | [rd bg1][stg B.kk0(T+1)] MM1
//   WVM(2) SB | same for kk1 | WVM(2) SB.  Tail: WVM(0).
// Cross-wave safety: reads consumed by pre-barrier MFMAs => retired at
// barrier; stages target other parity. EPI=0 bf16 C; EPI=1 fp32 C+bias.
// C = A (MxK rm) * B^T (B NxK rm). M,N%128==0, K=1024.
// ---------------------------------------------------------------------------
template <int EPI, int NP>
__global__ __launch_bounds__(512, 4)
void gemm128k(const bf16* __restrict__ A, const bf16* __restrict__ B,
              bf16* __restrict__ Cb, float* __restrict__ Cf,
              const float* __restrict__ bias_p, int M) {
  constexpr int KP = 1024;
  constexpr int NT = KP / 64;           // 16 K-tiles
  extern __shared__ char lds[];
  const int tid  = threadIdx.x;
  const int lane = tid & 63, wave = tid >> 6;
  const int wm = wave >> 1, wn = wave & 1;      // 4 x 2 waves
  const int fr = lane & 15, fq = lane >> 4;
  // R8-verified read-side lane byte offset within a line-pair structure
  const int laneb = (fr >> 1) * 128 + ((((fr & 1) * 4 + fq) ^ ((fr >> 1) & 7)) << 4);

  // ---- block -> output tile ----
  const int nwg = gridDim.x;
  const int bid = blockIdx.x;
  constexpr int gx = NP >> 7;
  const int nTiles = (M >> 7) * gx;
  int tr, tc;
  if (NP == 8192 && nwg == 4096) {
    const int set = bid >> 9, idx = bid & 511;
    const int xcd = idx & 7, pos = idx >> 3;    // pos 0..63
    tr = (set >> 1) * 16 + (xcd >> 2) * 8 + (pos >> 3);
    tc = (set & 1) * 32 + (xcd & 3) * 8 + (pos & 7);
  } else {
    const int swz = (bid & 7) * (nTiles >> 3) + (bid >> 3);
    tr = swz / gx; tc = swz % gx;
  }
  const int row0 = tr << 7, col0 = tc << 7;

  // ---- staging source (R8-verified paired-row mapping) ----
  const int gsw  = (tid & 7) ^ ((tid >> 3) & 7);
  const int srow = 2 * (tid >> 3) + (gsw >> 2);   // 0..127
  const int chnk = gsw & 3;                       // k-chunk within 32 cols
  const bf16* Agl = A + (size_t)(row0 + srow) * KP + chnk * 8;
  const bf16* Bgl = B + (size_t)(col0 + srow) * KP + chnk * 8;

  // stage one kk-half of tile t; base_off: A=0, B=32768 (bytes)
#define STG1(gp, base_off, t, kk)                                            \
  GLD_LDS((gp) + (size_t)(t) * 64 + (kk) * 32,                               \
          lds + (base_off) + ((t) & 1) * 16384 + (kk) * 8192 + wave * 1024)

  // ---- LDS read bases ----
  const char* Ab = lds + wm * 2048 + laneb;          // +p*16K +kk*8K +m*1K
  const char* Bb = lds + 32768 + wn * 4096 + laneb;  // +p*16K +kk*8K +n*1K

  f32x4  acc[2][4] = {};
  bf16x8 af[2], bg[4];

#define LDA(kk, p)                                                           \
  do {                                                                       \
    _Pragma("unroll") for (int m_ = 0; m_ < 2; ++m_)                         \
      af[m_] = *(const bf16x8*)(Ab + (p) * 16384 + (kk) * 8192 + m_ * 1024); \
  } while (0)

#define LDBH(np, kk, p)                                                      \
  do {                                                                       \
    _Pragma("unroll") for (int n_ = 0; n_ < 2; ++n_)                         \
      bg[(np) * 2 + n_] = *(const bf16x8*)(Bb + (p) * 16384 + (kk) * 8192 +  \
                                           ((np) * 2 + n_) * 1024);          \
  } while (0)

#define MM(np)                                                               \
  do {                                                                       \
    _Pragma("unroll") for (int m_ = 0; m_ < 2; ++m_)                         \
      _Pragma("unroll") for (int n_ = 0; n_ < 2; ++n_)                       \
        acc[m_][(np) * 2 + n_] = __builtin_amdgcn_mfma_f32_16x16x32_bf16(    \
            af[m_], bg[(np) * 2 + n_], acc[m_][(np) * 2 + n_], 0, 0, 0);     \
  } while (0)

  // prologue: T0 kk0 (A,B) then kk1 (A,B); WVM(2) drains kk0, leaves kk1
  STG1(Agl, 0, 0, 0); STG1(Bgl, 32768, 0, 0);
  STG1(Agl, 0, 0, 1); STG1(Bgl, 32768, 0, 1);
  WVM(2); SB();

  for (int T = 0; T < NT; ++T) {
    const int p = T & 1;
    const bool st = (T + 1 < NT);
    // half 1 (kk0 of T); stages kk0 of T+1
    LDA(0, p); LDBH(0, 0, p);
    if (st) STG1(Agl, 0, T + 1, 0);
    PRIO1(); MM(0); PRIO0();
    LDBH(1, 0, p);
    if (st) STG1(Bgl, 32768, T + 1, 0);
    PRIO1(); MM(1); PRIO0();
    if (st) { WVM(2); } else { WVM(0); }
    SB();
    // half 2 (kk1 of T); stages kk1 of T+1
    LDA(1, p); LDBH(0, 1, p);
    if (st) STG1(Agl, 0, T + 1, 1);
    PRIO1(); MM(0); PRIO0();
    LDBH(1, 1, p);
    if (st) STG1(Bgl, 32768, T + 1, 1);
    PRIO1(); MM(1); PRIO0();
    if (st) { WVM(2); } else { WVM(0); }
    SB();
  }

  // epilogue — C/D layout (verified): col = lane&15, row = (lane>>4)*4 + j
  const float bias = (EPI == 1) ? bias_p[0] : 0.0f;
#pragma unroll
  for (int m = 0; m < 2; ++m) {
#pragma unroll
    for (int n = 0; n < 4; ++n) {
      const int r = row0 + wm * 32 + m * 16 + fq * 4;
      const int c = col0 + wn * 64 + n * 16 + fr;
#pragma unroll
      for (int j = 0; j < 4; ++j) {
        if (EPI == 1)
          Cf[(size_t)(r + j) * NP + c] = acc[m][n][j] + bias;
        else
          Cb[(size_t)(r + j) * NP + c] = (bf16)acc[m][n][j];
      }
    }
  }
#undef STG1
#undef LDA
#undef LDBH
#undef MM
}

// fp32 -> bf16 cast, 4 elems/thread
__global__ void cvt_f32_bf16(const float* __restrict__ in, bf16* __restrict__ out,
                             int n4) {
  int i = blockIdx.x * blockDim.x + threadIdx.x;
  if (i >= n4) return;
  const float4 v = ((const float4*)in)[i];
  bf16x4 o;
  o[0] = (bf16)v.x; o[1] = (bf16)v.y; o[2] = (bf16)v.z; o[3] = (bf16)v.w;
  ((bf16x4*)out)[i] = o;
}

// Wt[n][k] = (bf16) W[k][n], 1024x1024
__global__ void transpose_cvt_w(const float* __restrict__ W, bf16* __restrict__ Wt) {
  __shared__ float s[32][33];
  const int tx = threadIdx.x & 31;
  const int ty = threadIdx.x >> 5;
  const int n0 = blockIdx.x * 32;
  const int k0 = blockIdx.y * 32;
#pragma unroll
  for (int p = 0; p < 4; ++p)
    s[ty + p * 8][tx] = W[(size_t)(k0 + ty + p * 8) * 1024 + n0 + tx];
  __syncthreads();
#pragma unroll
  for (int p = 0; p < 4; ++p)
    Wt[(size_t)(n0 + ty + p * 8) * 1024 + k0 + tx] = (bf16)s[tx][ty + p * 8];
}

extern "C" void kernel_launch(void* const* d_in, const int* in_sizes, int n_in,
                              void* d_out, int out_size, void* d_ws, size_t ws_size,
                              hipStream_t stream) {
  const float* X = (const float*)d_in[0];   // (8192, 1024)
  const float* W = (const float*)d_in[1];   // (1024, 1024)
  const float* b = (const float*)d_in[2];   // (1,)
  float* out = (float*)d_out;               // (8192, 8192)

  const int Nn = 8192, D = 1024;
  char* ws = (char*)d_ws;
  bf16* Xb  = (bf16*)(ws);
  bf16* XWb = (bf16*)(ws + (size_t)16 * 1024 * 1024);
  bf16* Wt  = (bf16*)(ws + (size_t)32 * 1024 * 1024);

  cvt_f32_bf16<<<(Nn * D / 4 + 255) / 256, 256, 0, stream>>>(X, Xb, Nn * D / 4);
  transpose_cvt_w<<<dim3(D / 32, D / 32), 256, 0, stream>>>(W, Wt);
  // GEMM1: XW = Xb * Wt^T  (8192x1024) -> bf16
  gemm128k<0, 1024><<<512, 512, 65536, stream>>>(Xb, Wt, XWb, nullptr, nullptr,
                                                 Nn);
  // GEMM2: out = XWb * Xb^T + b  (8192x8192) fp32; 4096 tiles, 2 blocks/CU
  gemm128k<1, 8192><<<4096, 512, 65536, stream>>>(XWb, Xb, nullptr, out, b, Nn);
}

// Round 15
// 194.566 us; speedup vs baseline: 1.1280x; 1.1280x over previous
//
#include <hip/hip_runtime.h>
#include <hip/hip_bf16.h>

typedef __bf16 bf16;
typedef __bf16 bf16x8 __attribute__((ext_vector_type(8)));
typedef __bf16 bf16x4 __attribute__((ext_vector_type(4)));
typedef float  f32x4  __attribute__((ext_vector_type(4)));

#define GLD_LDS(g, l)                                                        \
  __builtin_amdgcn_global_load_lds(                                          \
      (const __attribute__((address_space(1))) void*)(g),                    \
      (__attribute__((address_space(3))) void*)(l), 16, 0, 0)

#define SB()    __builtin_amdgcn_s_barrier()
#define WVM(n)  asm volatile("s_waitcnt vmcnt(" #n ")" ::: "memory")
#define PRIO1() __builtin_amdgcn_s_setprio(1)
#define PRIO0() __builtin_amdgcn_s_setprio(0)

// ---------------------------------------------------------------------------
// R12 persistent 256x256 8-phase kernel + LDS-COALESCED EPILOGUE (EPI=1).
// Rationale: vmcnt is a per-wave FIFO and maxes at 63. The old epilogue's
// 128 scalar dword stores (>63) forced every later gate (junction WVM(63),
// next tile's ph4 WVM(2)) to drain the store stream. New epilogue stages
// acc into LDS (B-buf1 region, byte [98304,131072) — free: its last K-loop
// read completes before ph8's closing barrier, and the folded next-tile
// prologue targets only A-buf0/B-buf0/A-buf1-lo), reads back row-contiguous,
// stores 32 x dwordx4 per thread. Junction gate WVM(32) then drains exactly
// the 10 prologue loads and NO stores.
//  - 8 chunks of 32 rows (32KB): waves wm==h write acc[q*2+mh][n][j] at
//    f32 idx rl*256 + (colL ^ (fq<<4)), rl=mh*16+fq*4+j, colL=wn*64+n*16+fr
//    (2-way banks = free); SB; all 512 threads read f32x4 at
//    rl*256 + ((lane*4) ^ (((rl>>2)&3)<<4)) (sequential, conflict-free),
//    add bias, store dwordx4; SB.  ((rl>>2)&3 == writer's fq — verified.)
// Everything else identical to R12 (verified absmax 0.5, 0 conflicts):
// compile-time K=1024/NP, running-pointer staging, no blanket lgkmcnt
// (compiler partial waits drain under MFMA), counted vmcnt(2) at ph4/ph8,
// ledger ph1 T+1.Ah1 | ph2 T+1.Bh0 | ph3 T+1.Bh1 | ph4 T+2.Ah0 | ph5
// T+2.Ah1 | ph6 T+2.Bh0 | ph7 T+2.Bh1 | ph8 T+3.Ah0; folded next-tile
// prologue in the peeled last iteration; supertile mapping (FETCH ~98MB).
// ---------------------------------------------------------------------------
template <int EPI, int NP>
__global__ __launch_bounds__(512, 2)
void gemm256(const bf16* __restrict__ A, const bf16* __restrict__ B,
             bf16* __restrict__ Cb, float* __restrict__ Cf,
             const float* __restrict__ bias_p, int M) {
  constexpr int KP = 1024;
  constexpr int NT = KP / 64;            // 16 K-tiles
  extern __shared__ bf16 lds[];
  const int tid  = threadIdx.x;
  const int lane = tid & 63, wave = tid >> 6;
  const int wm = wave >> 2, wn = wave & 3;       // 2 x 4 waves
  const int fr = lane & 15, fq = lane >> 4;
  const int xm = (fr & 7) << 4;
  const int kx0 = (fq * 16) ^ xm;
  const int kx1 = (fq * 16 + 64) ^ xm;

  const int nwg = gridDim.x;
  const int bid = blockIdx.x;
  constexpr int gx = NP >> 8;
  const int nTiles = (M >> 8) * gx;
  const int rounds = nTiles / nwg;

  // staging source lane geometry (pre-swizzled k-chunk)
  const int srow = wave * 8 + (lane >> 3);
  const int scol = ((lane & 7) ^ (lane >> 3)) * 8;

  // LDS bases
  bf16* ldsA = lds + wave * 512;
  bf16* ldsB = lds + 32768 + wave * 512;
  const char* ldsc = (const char*)lds;
  const char* Ab0 = ldsc + wm * 16384 + fr * 128 + kx0;
  const char* Ab1 = ldsc + wm * 16384 + fr * 128 + kx1;
  const char* Bb0 = ldsc + 65536 + wn * 8192 + fr * 128 + kx0;
  const char* Bb1 = ldsc + 65536 + wn * 8192 + fr * 128 + kx1;

  const float bias = (EPI == 1) ? bias_p[0] : 0.0f;

#define STG2(p0, p1, trel, base, off)                                        \
  do {                                                                       \
    GLD_LDS((p0) + (trel) * 64, (base) + (off));                             \
    GLD_LDS((p1) + (trel) * 64, (base) + (off) + 4096);                      \
  } while (0)

#define LDA4(mg, kk, p)                                                      \
  do {                                                                       \
    _Pragma("unroll") for (int m_ = 0; m_ < 4; ++m_)                         \
      af[m_][kk] = *(const bf16x8*)(Ab##kk + (p) * 32768 +                   \
                                    ((mg) * 4 + m_) * 2048);                 \
  } while (0)

#define LDB2(np, kk, p)                                                      \
  do {                                                                       \
    _Pragma("unroll") for (int n_ = 0; n_ < 2; ++n_)                         \
      bg[(np) * 2 + n_][kk] = *(const bf16x8*)(Bb##kk + (p) * 32768 +        \
                                               ((np) * 2 + n_) * 2048);      \
  } while (0)

#define MM(mg, np)                                                           \
  do {                                                                       \
    _Pragma("unroll") for (int kk_ = 0; kk_ < 2; ++kk_)                      \
      _Pragma("unroll") for (int m_ = 0; m_ < 4; ++m_)                       \
        _Pragma("unroll") for (int n_ = 0; n_ < 2; ++n_)                     \
          acc[(mg) * 4 + m_][(np) * 2 + n_] =                                \
              __builtin_amdgcn_mfma_f32_16x16x32_bf16(                       \
                  af[m_][kk_], bg[(np) * 2 + n_][kk_],                       \
                  acc[(mg) * 4 + m_][(np) * 2 + n_], 0, 0, 0);               \
  } while (0)

#define PHASE(RDS, STAGE, MMC, GATE)                                         \
  do { RDS; STAGE; SB(); PRIO1(); MMC; PRIO0(); GATE; SB(); } while (0)

#define RD1 do { LDB2(0,0,0); LDA4(0,0,0); LDB2(0,1,0); LDA4(0,1,0); } while(0)
#define RD2 do { LDB2(1,0,0); LDB2(1,1,0); } while(0)
#define RD3 do { LDA4(1,0,0); LDA4(1,1,0); } while(0)
#define RD5 do { LDB2(0,0,1); LDA4(0,0,1); LDB2(0,1,1); LDA4(0,1,1); } while(0)
#define RD6 do { LDB2(1,0,1); LDB2(1,1,1); } while(0)
#define RD7 do { LDA4(1,0,1); LDA4(1,1,1); } while(0)

  // ---- tile mapping ----
  auto mapTile = [&](int rd, int& tr, int& tc) {
    if (NP == 8192 && nwg == 256 && (M >> 8) == 32) {
      const int xcd = bid & 7, pos = bid >> 3;
      tr = (rd >> 1) * 16 + (xcd >> 1) * 4 + (pos >> 3);
      tc = (rd & 1) * 16 + (xcd & 1) * 8 + (pos & 7);
    } else {
      const int li = rd * nwg + bid;
      const int swz = (li & 7) * (nTiles >> 3) + (li >> 3);
      tr = li < nTiles ? swz / gx : 0; tc = li < nTiles ? swz % gx : 0;
    }
  };

  int tr, tc;
  mapTile(0, tr, tc);
  int row0 = tr << 8, col0 = tc << 8;

  const bf16* a0 = A + (size_t)(row0 + srow) * KP + scol;
  const bf16* a1 = a0 + (size_t)64 * KP;
  const bf16* a2 = a0 + (size_t)128 * KP;
  const bf16* a3 = a0 + (size_t)192 * KP;
  const bf16* b0 = B + (size_t)(col0 + srow) * KP + scol;
  const bf16* b1 = b0 + (size_t)64 * KP;
  const bf16* b2 = b0 + (size_t)128 * KP;
  const bf16* b3 = b0 + (size_t)192 * KP;

  // prologue: T0 (4 halves) + T1.Ah0
  STG2(a0, a1, 0, ldsA, 0);
  STG2(a2, a3, 0, ldsA, 8192);
  STG2(b0, b1, 0, ldsB, 0);
  STG2(b2, b3, 0, ldsB, 8192);
  STG2(a0, a1, 1, ldsA, 16384);

  for (int rd = 0; rd < rounds; ++rd) {
    if (rd == 0) { WVM(2); } else { WVM(32); }
    SB();

    f32x4  acc[8][4] = {};
    bf16x8 af[4][2];
    bf16x8 bg[4][2];

#pragma unroll 1
    for (int it = 0; it < NT / 2 - 1; ++it) {
      PHASE(RD1, STG2(a2, a3, 1, ldsA, 24576), MM(0, 0), );
      PHASE(RD2, STG2(b0, b1, 1, ldsB, 16384), MM(0, 1), );
      PHASE(RD3, STG2(b2, b3, 1, ldsB, 24576), MM(1, 0), );
      PHASE(   , STG2(a0, a1, 2, ldsA, 0),     MM(1, 1), WVM(2));
      PHASE(RD5, STG2(a2, a3, 2, ldsA, 8192),  MM(0, 0), );
      PHASE(RD6, STG2(b0, b1, 2, ldsB, 0),     MM(0, 1), );
      PHASE(RD7, STG2(b2, b3, 2, ldsB, 8192),  MM(1, 0), );
      PHASE(   , STG2(a0, a1, 3, ldsA, 16384), MM(1, 1), WVM(2));
      a0 += 128; a1 += 128; a2 += 128; a3 += 128;
      b0 += 128; b1 += 128; b2 += 128; b3 += 128;
    }

    // peeled last iteration: stage NEXT tile's prologue in ph4-ph8 slots
    const bool hn = (rd + 1 < rounds);
    int ntr, ntc;
    mapTile(rd + 1, ntr, ntc);
    const int nrow0 = ntr << 8, ncol0 = ntc << 8;
    const bf16* na0 = A + (size_t)(nrow0 + srow) * KP + scol;
    const bf16* na1 = na0 + (size_t)64 * KP;
    const bf16* na2 = na0 + (size_t)128 * KP;
    const bf16* na3 = na0 + (size_t)192 * KP;
    const bf16* nb0 = B + (size_t)(ncol0 + srow) * KP + scol;
    const bf16* nb1 = nb0 + (size_t)64 * KP;
    const bf16* nb2 = nb0 + (size_t)128 * KP;
    const bf16* nb3 = nb0 + (size_t)192 * KP;

    PHASE(RD1, STG2(a2, a3, 1, ldsA, 24576), MM(0, 0), );
    PHASE(RD2, STG2(b0, b1, 1, ldsB, 16384), MM(0, 1), );
    PHASE(RD3, STG2(b2, b3, 1, ldsB, 24576), MM(1, 0), );
    PHASE(   , if (hn) { STG2(na0, na1, 0, ldsA, 0); },    MM(1, 1),
           if (hn) { WVM(2); } else { WVM(0); });
    PHASE(RD5, if (hn) { STG2(na2, na3, 0, ldsA, 8192); }, MM(0, 0), );
    PHASE(RD6, if (hn) { STG2(nb0, nb1, 0, ldsB, 0); },    MM(0, 1), );
    PHASE(RD7, if (hn) { STG2(nb2, nb3, 0, ldsB, 8192); }, MM(1, 0), );
    PHASE(   , if (hn) { STG2(na0, na1, 1, ldsA, 16384); }, MM(1, 1),
           if (hn) { WVM(2); } else { WVM(0); });

    if (EPI == 1) {
      // ---- LDS-coalesced epilogue (B-buf1 scratch, byte 98304+) ----
      float* ldse = (float*)(ldsc + 98304);
#pragma unroll
      for (int q2 = 0; q2 < 8; ++q2) {
        const int h = q2 >> 2, q = q2 & 3;
        if (wm == h) {
#pragma unroll
          for (int mh = 0; mh < 2; ++mh)
#pragma unroll
            for (int n = 0; n < 4; ++n)
#pragma unroll
              for (int j = 0; j < 4; ++j) {
                const int rl = mh * 16 + fq * 4 + j;
                const int cl = (wn * 64 + n * 16 + fr) ^ (fq << 4);
                ldse[rl * 256 + cl] = acc[q * 2 + mh][n][j];
              }
        }
        SB();
#pragma unroll
        for (int i = 0; i < 4; ++i) {
          const int rl = i * 8 + wave;
          const int s = (rl >> 2) & 3;
          const f32x4 v =
              *(const f32x4*)&ldse[rl * 256 + ((lane * 4) ^ (s << 4))];
          f32x4 o;
          o[0] = v[0] + bias; o[1] = v[1] + bias;
          o[2] = v[2] + bias; o[3] = v[3] + bias;
          *(f32x4*)&Cf[(size_t)(row0 + h * 128 + q * 32 + rl) * NP + col0 +
                       lane * 4] = o;
        }
        SB();
      }
    } else {
      // bf16 epilogue (GEMM1) — C/D layout: col = lane&15, row=(lane>>4)*4+j
#pragma unroll
      for (int m = 0; m < 8; ++m) {
#pragma unroll
        for (int n = 0; n < 4; ++n) {
          const int r = row0 + wm * 128 + m * 16 + fq * 4;
          const int c = col0 + wn * 64 + n * 16 + fr;
#pragma unroll
          for (int j = 0; j < 4; ++j)
            Cb[(size_t)(r + j) * NP + c] = (bf16)acc[m][n][j];
        }
      }
    }

    // advance to next tile
    a0 = na0; a1 = na1; a2 = na2; a3 = na3;
    b0 = nb0; b1 = nb1; b2 = nb2; b3 = nb3;
    row0 = nrow0; col0 = ncol0;
  }
#undef STG2
#undef LDA4
#undef LDB2
#undef MM
#undef PHASE
#undef RD1
#undef RD2
#undef RD3
#undef RD5
#undef RD6
#undef RD7
}

// fp32 -> bf16 cast, 4 elems/thread
__global__ void cvt_f32_bf16(const float* __restrict__ in, bf16* __restrict__ out,
                             int n4) {
  int i = blockIdx.x * blockDim.x + threadIdx.x;
  if (i >= n4) return;
  const float4 v = ((const float4*)in)[i];
  bf16x4 o;
  o[0] = (bf16)v.x; o[1] = (bf16)v.y; o[2] = (bf16)v.z; o[3] = (bf16)v.w;
  ((bf16x4*)out)[i] = o;
}

// Wt[n][k] = (bf16) W[k][n], 1024x1024
__global__ void transpose_cvt_w(const float* __restrict__ W, bf16* __restrict__ Wt) {
  __shared__ float s[32][33];
  const int tx = threadIdx.x & 31;
  const int ty = threadIdx.x >> 5;
  const int n0 = blockIdx.x * 32;
  const int k0 = blockIdx.y * 32;
#pragma unroll
  for (int p = 0; p < 4; ++p)
    s[ty + p * 8][tx] = W[(size_t)(k0 + ty + p * 8) * 1024 + n0 + tx];
  __syncthreads();
#pragma unroll
  for (int p = 0; p < 4; ++p)
    Wt[(size_t)(n0 + ty + p * 8) * 1024 + k0 + tx] = (bf16)s[tx][ty + p * 8];
}

extern "C" void kernel_launch(void* const* d_in, const int* in_sizes, int n_in,
                              void* d_out, int out_size, void* d_ws, size_t ws_size,
                              hipStream_t stream) {
  const float* X = (const float*)d_in[0];   // (8192, 1024)
  const float* W = (const float*)d_in[1];   // (1024, 1024)
  const float* b = (const float*)d_in[2];   // (1,)
  float* out = (float*)d_out;               // (8192, 8192)

  const int Nn = 8192, D = 1024;
  char* ws = (char*)d_ws;
  bf16* Xb  = (bf16*)(ws);
  bf16* XWb = (bf16*)(ws + (size_t)16 * 1024 * 1024);
  bf16* Wt  = (bf16*)(ws + (size_t)32 * 1024 * 1024);

  cvt_f32_bf16<<<(Nn * D / 4 + 255) / 256, 256, 0, stream>>>(X, Xb, Nn * D / 4);
  transpose_cvt_w<<<dim3(D / 32, D / 32), 256, 0, stream>>>(W, Wt);
  // GEMM1: XW = Xb * Wt^T  (8192x1024, K=1024) -> bf16; 128 blocks, 1 round
  gemm256<0, 1024><<<128, 512, 131072, stream>>>(Xb, Wt, XWb, nullptr, nullptr,
                                                 Nn);
  // GEMM2: out = XWb * Xb^T + b  (8192x8192) fp32; 256 persistent blocks x 4
  gemm256<1, 8192><<<256, 512, 131072, stream>>>(XWb, Xb, nullptr, out, b, Nn);
}

// Round 16
// 192.095 us; speedup vs baseline: 1.1425x; 1.0129x over previous
//
#include <hip/hip_runtime.h>
#include <hip/hip_bf16.h>

typedef __bf16 bf16;
typedef __bf16 bf16x8 __attribute__((ext_vector_type(8)));
typedef __bf16 bf16x4 __attribute__((ext_vector_type(4)));
typedef float  f32x4  __attribute__((ext_vector_type(4)));

#define GLD_LDS(g, l)                                                        \
  __builtin_amdgcn_global_load_lds(                                          \
      (const __attribute__((address_space(1))) void*)(g),                    \
      (__attribute__((address_space(3))) void*)(l), 16, 0, 0)

#define SB()    __builtin_amdgcn_s_barrier()
#define WVM(n)  asm volatile("s_waitcnt vmcnt(" #n ")" ::: "memory")
#define PRIO1() __builtin_amdgcn_s_setprio(1)
#define PRIO0() __builtin_amdgcn_s_setprio(0)

// ---------------------------------------------------------------------------
// gemm256 v16: NON-PERSISTENT single-tile blocks (cross-block junction
// overlap: a retiring block's store drain and the next block's prologue are
// different waves -> independent vmcnt FIFOs and barriers; the CU interleaves
// them, which intra-block scheduling could not do at 1 block/CU).
// Components, all previously verified on this problem:
//  - R12 in-loop phase structure: compile-time K=1024/NP, running-pointer +
//    literal-offset addressing, NO blanket lgkmcnt (compiler partial waits
//    drain LDS reads under the MFMA burst), counted WVM(2) at ph4/ph8
//    (every drained load is >=3 phases old - gates never block),
//    builtin barriers, setprio around MFMA clusters.
//  - R10 supertile map (GEMM2 @1024 blocks): round=bid>>8 -> 16x16 tile
//    supertile, XCD-compact 4x8 regions (FETCH ~98MB).
//  - R15 LDS-coalesced epilogue (EPI=1): acc -> B-buf1 LDS scratch (free
//    after ph8's closing barrier) -> 32 x global_store_dwordx4; absmax 0.5.
// Ledger (verified): ph1 T+1.Ah1 | ph2 T+1.Bh0 | ph3 T+1.Bh1 | ph4 T+2.Ah0
// +WVM2 | ph5 T+2.Ah1 | ph6 T+2.Bh0 | ph7 T+2.Bh1 | ph8 T+3.Ah0 +WVM2;
// peeled last pair stages only T+1 halves, gates WVM(0).
// LDS 128K: A dbuf @0, B dbuf @65536; XOR swizzle byte bits4-6 ^= row&7 on
// reads, staging pre-swizzles the global k-chunk (rule #21 both-sides).
// EPI=0: bf16 C. EPI=1: fp32 C + bias. C = A*B^T. M,N%256==0, K=1024.
// ---------------------------------------------------------------------------
template <int EPI, int NP>
__global__ __launch_bounds__(512, 2)
void gemm256(const bf16* __restrict__ A, const bf16* __restrict__ B,
             bf16* __restrict__ Cb, float* __restrict__ Cf,
             const float* __restrict__ bias_p, int M) {
  constexpr int KP = 1024;
  constexpr int NT = KP / 64;            // 16 K-tiles
  extern __shared__ bf16 lds[];
  const int tid  = threadIdx.x;
  const int lane = tid & 63, wave = tid >> 6;
  const int wm = wave >> 2, wn = wave & 3;       // 2 x 4 waves
  const int fr = lane & 15, fq = lane >> 4;
  const int xm = (fr & 7) << 4;
  const int kx0 = (fq * 16) ^ xm;
  const int kx1 = (fq * 16 + 64) ^ xm;

  const int bid = blockIdx.x;
  constexpr int gx = NP >> 8;

  // ---- block -> output tile ----
  int tr, tc;
  if (NP == 8192 && gridDim.x == 1024) {
    const int round = bid >> 8, idx = bid & 255;
    const int xcd = idx & 7, pos = idx >> 3;     // pos 0..31
    tr = (round >> 1) * 16 + (xcd >> 1) * 4 + (pos >> 3);
    tc = (round & 1) * 16 + (xcd & 1) * 8 + (pos & 7);
  } else {
    const int nTiles = (M >> 8) * gx;
    const int swz = (bid & 7) * (nTiles >> 3) + (bid >> 3);
    tr = swz / gx; tc = swz % gx;
  }
  const int row0 = tr << 8, col0 = tc << 8;

  // staging source lane geometry (pre-swizzled k-chunk)
  const int srow = wave * 8 + (lane >> 3);
  const int scol = ((lane & 7) ^ (lane >> 3)) * 8;

  // LDS bases
  bf16* ldsA = lds + wave * 512;
  bf16* ldsB = lds + 32768 + wave * 512;
  const char* ldsc = (const char*)lds;
  const char* Ab0 = ldsc + wm * 16384 + fr * 128 + kx0;
  const char* Ab1 = ldsc + wm * 16384 + fr * 128 + kx1;
  const char* Bb0 = ldsc + 65536 + wn * 8192 + fr * 128 + kx0;
  const char* Bb1 = ldsc + 65536 + wn * 8192 + fr * 128 + kx1;

  const float bias = (EPI == 1) ? bias_p[0] : 0.0f;

#define STG2(p0, p1, trel, base, off)                                        \
  do {                                                                       \
    GLD_LDS((p0) + (trel) * 64, (base) + (off));                             \
    GLD_LDS((p1) + (trel) * 64, (base) + (off) + 4096);                      \
  } while (0)

#define LDA4(mg, kk, p)                                                      \
  do {                                                                       \
    _Pragma("unroll") for (int m_ = 0; m_ < 4; ++m_)                         \
      af[m_][kk] = *(const bf16x8*)(Ab##kk + (p) * 32768 +                   \
                                    ((mg) * 4 + m_) * 2048);                 \
  } while (0)

#define LDB2(np, kk, p)                                                      \
  do {                                                                       \
    _Pragma("unroll") for (int n_ = 0; n_ < 2; ++n_)                         \
      bg[(np) * 2 + n_][kk] = *(const bf16x8*)(Bb##kk + (p) * 32768 +        \
                                               ((np) * 2 + n_) * 2048);      \
  } while (0)

#define MM(mg, np)                                                           \
  do {                                                                       \
    _Pragma("unroll") for (int kk_ = 0; kk_ < 2; ++kk_)                      \
      _Pragma("unroll") for (int m_ = 0; m_ < 4; ++m_)                       \
        _Pragma("unroll") for (int n_ = 0; n_ < 2; ++n_)                     \
          acc[(mg) * 4 + m_][(np) * 2 + n_] =                                \
              __builtin_amdgcn_mfma_f32_16x16x32_bf16(                       \
                  af[m_][kk_], bg[(np) * 2 + n_][kk_],                       \
                  acc[(mg) * 4 + m_][(np) * 2 + n_], 0, 0, 0);               \
  } while (0)

#define PHASE(RDS, STAGE, MMC, GATE)                                         \
  do { RDS; STAGE; SB(); PRIO1(); MMC; PRIO0(); GATE; SB(); } while (0)

#define RD1 do { LDB2(0,0,0); LDA4(0,0,0); LDB2(0,1,0); LDA4(0,1,0); } while(0)
#define RD2 do { LDB2(1,0,0); LDB2(1,1,0); } while(0)
#define RD3 do { LDA4(1,0,0); LDA4(1,1,0); } while(0)
#define RD5 do { LDB2(0,0,1); LDA4(0,0,1); LDB2(0,1,1); LDA4(0,1,1); } while(0)
#define RD6 do { LDB2(1,0,1); LDB2(1,1,1); } while(0)
#define RD7 do { LDA4(1,0,1); LDA4(1,1,1); } while(0)

  const bf16* a0 = A + (size_t)(row0 + srow) * KP + scol;
  const bf16* a1 = a0 + (size_t)64 * KP;
  const bf16* a2 = a0 + (size_t)128 * KP;
  const bf16* a3 = a0 + (size_t)192 * KP;
  const bf16* b0 = B + (size_t)(col0 + srow) * KP + scol;
  const bf16* b1 = b0 + (size_t)64 * KP;
  const bf16* b2 = b0 + (size_t)128 * KP;
  const bf16* b3 = b0 + (size_t)192 * KP;

  // prologue: T0 (4 halves) + T1.Ah0 = 10 loads; keep newest 2 in flight
  STG2(a0, a1, 0, ldsA, 0);
  STG2(a2, a3, 0, ldsA, 8192);
  STG2(b0, b1, 0, ldsB, 0);
  STG2(b2, b3, 0, ldsB, 8192);
  STG2(a0, a1, 1, ldsA, 16384);
  WVM(2); SB();

  f32x4  acc[8][4] = {};
  bf16x8 af[4][2];
  bf16x8 bg[4][2];

#pragma unroll 1
  for (int it = 0; it < NT / 2 - 1; ++it) {
    PHASE(RD1, STG2(a2, a3, 1, ldsA, 24576), MM(0, 0), );
    PHASE(RD2, STG2(b0, b1, 1, ldsB, 16384), MM(0, 1), );
    PHASE(RD3, STG2(b2, b3, 1, ldsB, 24576), MM(1, 0), );
    PHASE(   , STG2(a0, a1, 2, ldsA, 0),     MM(1, 1), WVM(2));
    PHASE(RD5, STG2(a2, a3, 2, ldsA, 8192),  MM(0, 0), );
    PHASE(RD6, STG2(b0, b1, 2, ldsB, 0),     MM(0, 1), );
    PHASE(RD7, STG2(b2, b3, 2, ldsB, 8192),  MM(1, 0), );
    PHASE(   , STG2(a0, a1, 3, ldsA, 16384), MM(1, 1), WVM(2));
    a0 += 128; a1 += 128; a2 += 128; a3 += 128;
    b0 += 128; b1 += 128; b2 += 128; b3 += 128;
  }

  // peeled last pair (tiles NT-2, NT-1): stage only T+1 halves; drain gates
  PHASE(RD1, STG2(a2, a3, 1, ldsA, 24576), MM(0, 0), );
  PHASE(RD2, STG2(b0, b1, 1, ldsB, 16384), MM(0, 1), );
  PHASE(RD3, STG2(b2, b3, 1, ldsB, 24576), MM(1, 0), );
  PHASE(   ,                              , MM(1, 1), WVM(0));
  PHASE(RD5,                              , MM(0, 0), );
  PHASE(RD6,                              , MM(0, 1), );
  PHASE(RD7,                              , MM(1, 0), );
  PHASE(   ,                              , MM(1, 1), WVM(0));

  if (EPI == 1) {
    // ---- LDS-coalesced epilogue (B-buf1 scratch, byte 98304+) ----
    float* ldse = (float*)(ldsc + 98304);
#pragma unroll
    for (int q2 = 0; q2 < 8; ++q2) {
      const int h = q2 >> 2, q = q2 & 3;
      if (wm == h) {
#pragma unroll
        for (int mh = 0; mh < 2; ++mh)
#pragma unroll
          for (int n = 0; n < 4; ++n)
#pragma unroll
            for (int j = 0; j < 4; ++j) {
              const int rl = mh * 16 + fq * 4 + j;
              const int cl = (wn * 64 + n * 16 + fr) ^ (fq << 4);
              ldse[rl * 256 + cl] = acc[q * 2 + mh][n][j];
            }
      }
      SB();
#pragma unroll
      for (int i = 0; i < 4; ++i) {
        const int rl = i * 8 + wave;
        const int s = (rl >> 2) & 3;
        const f32x4 v =
            *(const f32x4*)&ldse[rl * 256 + ((lane * 4) ^ (s << 4))];
        f32x4 o;
        o[0] = v[0] + bias; o[1] = v[1] + bias;
        o[2] = v[2] + bias; o[3] = v[3] + bias;
        *(f32x4*)&Cf[(size_t)(row0 + h * 128 + q * 32 + rl) * NP + col0 +
                     lane * 4] = o;
      }
      SB();
    }
  } else {
    // bf16 epilogue (GEMM1) — C/D layout: col = lane&15, row = (lane>>4)*4+j
#pragma unroll
    for (int m = 0; m < 8; ++m) {
#pragma unroll
      for (int n = 0; n < 4; ++n) {
        const int r = row0 + wm * 128 + m * 16 + fq * 4;
        const int c = col0 + wn * 64 + n * 16 + fr;
#pragma unroll
        for (int j = 0; j < 4; ++j)
          Cb[(size_t)(r + j) * NP + c] = (bf16)acc[m][n][j];
      }
    }
  }
#undef STG2
#undef LDA4
#undef LDB2
#undef MM
#undef PHASE
#undef RD1
#undef RD2
#undef RD3
#undef RD5
#undef RD6
#undef RD7
}

// ---------------------------------------------------------------------------
// prep: fused X->bf16 cast (blocks [0,8192)) + W transpose+cast (blocks
// [8192,9216)); saves one kernel-launch gap.
// ---------------------------------------------------------------------------
__global__ void prep(const float* __restrict__ X, bf16* __restrict__ Xb,
                     const float* __restrict__ W, bf16* __restrict__ Wt) {
  __shared__ float s[32][33];
  const int bid = blockIdx.x;
  if (bid < 8192) {
    const int i = bid * 256 + threadIdx.x;     // < 2M quads
    const float4 v = ((const float4*)X)[i];
    bf16x4 o;
    o[0] = (bf16)v.x; o[1] = (bf16)v.y; o[2] = (bf16)v.z; o[3] = (bf16)v.w;
    ((bf16x4*)Xb)[i] = o;
  } else {
    const int b2 = bid - 8192;
    const int tx = threadIdx.x & 31;
    const int ty = threadIdx.x >> 5;
    const int n0 = (b2 & 31) * 32;
    const int k0 = (b2 >> 5) * 32;
#pragma unroll
    for (int p = 0; p < 4; ++p)
      s[ty + p * 8][tx] = W[(size_t)(k0 + ty + p * 8) * 1024 + n0 + tx];
    __syncthreads();
#pragma unroll
    for (int p = 0; p < 4; ++p)
      Wt[(size_t)(n0 + ty + p * 8) * 1024 + k0 + tx] = (bf16)s[tx][ty + p * 8];
  }
}

extern "C" void kernel_launch(void* const* d_in, const int* in_sizes, int n_in,
                              void* d_out, int out_size, void* d_ws, size_t ws_size,
                              hipStream_t stream) {
  const float* X = (const float*)d_in[0];   // (8192, 1024)
  const float* W = (const float*)d_in[1];   // (1024, 1024)
  const float* b = (const float*)d_in[2];   // (1,)
  float* out = (float*)d_out;               // (8192, 8192)

  const int Nn = 8192;
  char* ws = (char*)d_ws;
  bf16* Xb  = (bf16*)(ws);
  bf16* XWb = (bf16*)(ws + (size_t)16 * 1024 * 1024);
  bf16* Wt  = (bf16*)(ws + (size_t)32 * 1024 * 1024);

  // X->bf16 and W->Wt (fused)
  prep<<<9216, 256, 0, stream>>>(X, Xb, W, Wt);
  // GEMM1: XW = Xb * Wt^T  (8192x1024, K=1024) -> bf16; 128 blocks
  gemm256<0, 1024><<<128, 512, 131072, stream>>>(Xb, Wt, XWb, nullptr, nullptr,
                                                 Nn);
  // GEMM2: out = XWb * Xb^T + b  (8192x8192) fp32; 1024 single-tile blocks
  gemm256<1, 8192><<<1024, 512, 131072, stream>>>(XWb, Xb, nullptr, out, b, Nn);
}

// Round 18
// 182.239 us; speedup vs baseline: 1.2043x; 1.0541x over previous
//
#include <hip/hip_runtime.h>
#include <hip/hip_bf16.h>

typedef __bf16 bf16;
typedef __bf16 bf16x8 __attribute__((ext_vector_type(8)));
typedef __bf16 bf16x4 __attribute__((ext_vector_type(4)));
typedef float  f32x4  __attribute__((ext_vector_type(4)));

#define GLD_LDS(g, l)                                                        \
  __builtin_amdgcn_global_load_lds(                                          \
      (const __attribute__((address_space(1))) void*)(g),                    \
      (__attribute__((address_space(3))) void*)(l), 16, 0, 0)

#define SB()    __builtin_amdgcn_s_barrier()
#define WVM(n)  asm volatile("s_waitcnt vmcnt(" #n ")" ::: "memory")
#define PRIO1() __builtin_amdgcn_s_setprio(1)
#define PRIO0() __builtin_amdgcn_s_setprio(0)

// single TU-wide dynamic LDS symbol (char: both kernels cast as needed)
extern __shared__ char lds[];

// ---------------------------------------------------------------------------
// GEMM2 kernel: R12-verified persistent 256x256 8-phase (best measured:
// ~150us, MfmaUtil 37%, 0 conflicts, absmax 0.5). Verbatim from R12 except
// the shared-symbol type (bf16* ldsh = (bf16*)lds keeps all offsets).
// ---------------------------------------------------------------------------
template <int EPI, int NP>
__global__ __launch_bounds__(512, 2)
void gemm256(const bf16* __restrict__ A, const bf16* __restrict__ B,
             bf16* __restrict__ Cb, float* __restrict__ Cf,
             const float* __restrict__ bias_p, int M) {
  constexpr int KP = 1024;
  constexpr int NT = KP / 64;            // 16 K-tiles
  bf16* ldsh = (bf16*)lds;
  const int tid  = threadIdx.x;
  const int lane = tid & 63, wave = tid >> 6;
  const int wm = wave >> 2, wn = wave & 3;       // 2 x 4 waves
  const int fr = lane & 15, fq = lane >> 4;
  const int xm = (fr & 7) << 4;
  const int kx0 = (fq * 16) ^ xm;
  const int kx1 = (fq * 16 + 64) ^ xm;

  const int nwg = gridDim.x;
  const int bid = blockIdx.x;
  constexpr int gx = NP >> 8;
  const int nTiles = (M >> 8) * gx;
  const int rounds = nTiles / nwg;

  const int srow = wave * 8 + (lane >> 3);
  const int scol = ((lane & 7) ^ (lane >> 3)) * 8;

  bf16* ldsA = ldsh + wave * 512;
  bf16* ldsB = ldsh + 32768 + wave * 512;
  const char* ldsc = (const char*)ldsh;
  const char* Ab0 = ldsc + wm * 16384 + fr * 128 + kx0;
  const char* Ab1 = ldsc + wm * 16384 + fr * 128 + kx1;
  const char* Bb0 = ldsc + 65536 + wn * 8192 + fr * 128 + kx0;
  const char* Bb1 = ldsc + 65536 + wn * 8192 + fr * 128 + kx1;

  const float bias = (EPI == 1) ? bias_p[0] : 0.0f;

#define STG2(p0, p1, trel, base, off)                                        \
  do {                                                                       \
    GLD_LDS((p0) + (trel) * 64, (base) + (off));                             \
    GLD_LDS((p1) + (trel) * 64, (base) + (off) + 4096);                      \
  } while (0)

#define LDA4(mg, kk, p)                                                      \
  do {                                                                       \
    _Pragma("unroll") for (int m_ = 0; m_ < 4; ++m_)                         \
      af[m_][kk] = *(const bf16x8*)(Ab##kk + (p) * 32768 +                   \
                                    ((mg) * 4 + m_) * 2048);                 \
  } while (0)

#define LDB2(np, kk, p)                                                      \
  do {                                                                       \
    _Pragma("unroll") for (int n_ = 0; n_ < 2; ++n_)                         \
      bg[(np) * 2 + n_][kk] = *(const bf16x8*)(Bb##kk + (p) * 32768 +        \
                                               ((np) * 2 + n_) * 2048);      \
  } while (0)

#define MM(mg, np)                                                           \
  do {                                                                       \
    _Pragma("unroll") for (int kk_ = 0; kk_ < 2; ++kk_)                      \
      _Pragma("unroll") for (int m_ = 0; m_ < 4; ++m_)                       \
        _Pragma("unroll") for (int n_ = 0; n_ < 2; ++n_)                     \
          acc[(mg) * 4 + m_][(np) * 2 + n_] =                                \
              __builtin_amdgcn_mfma_f32_16x16x32_bf16(                       \
                  af[m_][kk_], bg[(np) * 2 + n_][kk_],                       \
                  acc[(mg) * 4 + m_][(np) * 2 + n_], 0, 0, 0);               \
  } while (0)

#define PHASE(RDS, STAGE, MMC, GATE)                                         \
  do { RDS; STAGE; SB(); PRIO1(); MMC; PRIO0(); GATE; SB(); } while (0)

#define RD1 do { LDB2(0,0,0); LDA4(0,0,0); LDB2(0,1,0); LDA4(0,1,0); } while(0)
#define RD2 do { LDB2(1,0,0); LDB2(1,1,0); } while(0)
#define RD3 do { LDA4(1,0,0); LDA4(1,1,0); } while(0)
#define RD5 do { LDB2(0,0,1); LDA4(0,0,1); LDB2(0,1,1); LDA4(0,1,1); } while(0)
#define RD6 do { LDB2(1,0,1); LDB2(1,1,1); } while(0)
#define RD7 do { LDA4(1,0,1); LDA4(1,1,1); } while(0)

  auto mapTile = [&](int rd, int& tr, int& tc) {
    if (NP == 8192 && nwg == 256 && (M >> 8) == 32) {
      const int xcd = bid & 7, pos = bid >> 3;
      tr = (rd >> 1) * 16 + (xcd >> 1) * 4 + (pos >> 3);
      tc = (rd & 1) * 16 + (xcd & 1) * 8 + (pos & 7);
    } else {
      const int li = rd * nwg + bid;
      const int swz = (li & 7) * (nTiles >> 3) + (li >> 3);
      tr = li < nTiles ? swz / gx : 0; tc = li < nTiles ? swz % gx : 0;
    }
  };

  int tr, tc;
  mapTile(0, tr, tc);
  int row0 = tr << 8, col0 = tc << 8;

  const bf16* a0 = A + (size_t)(row0 + srow) * KP + scol;
  const bf16* a1 = a0 + (size_t)64 * KP;
  const bf16* a2 = a0 + (size_t)128 * KP;
  const bf16* a3 = a0 + (size_t)192 * KP;
  const bf16* b0 = B + (size_t)(col0 + srow) * KP + scol;
  const bf16* b1 = b0 + (size_t)64 * KP;
  const bf16* b2 = b0 + (size_t)128 * KP;
  const bf16* b3 = b0 + (size_t)192 * KP;

  STG2(a0, a1, 0, ldsA, 0);
  STG2(a2, a3, 0, ldsA, 8192);
  STG2(b0, b1, 0, ldsB, 0);
  STG2(b2, b3, 0, ldsB, 8192);
  STG2(a0, a1, 1, ldsA, 16384);

  for (int rd = 0; rd < rounds; ++rd) {
    if (rd == 0) { WVM(2); } else { WVM(63); }
    SB();

    f32x4  acc[8][4] = {};
    bf16x8 af[4][2];
    bf16x8 bg[4][2];

#pragma unroll 1
    for (int it = 0; it < NT / 2 - 1; ++it) {
      PHASE(RD1, STG2(a2, a3, 1, ldsA, 24576), MM(0, 0), );
      PHASE(RD2, STG2(b0, b1, 1, ldsB, 16384), MM(0, 1), );
      PHASE(RD3, STG2(b2, b3, 1, ldsB, 24576), MM(1, 0), );
      PHASE(   , STG2(a0, a1, 2, ldsA, 0),     MM(1, 1), WVM(2));
      PHASE(RD5, STG2(a2, a3, 2, ldsA, 8192),  MM(0, 0), );
      PHASE(RD6, STG2(b0, b1, 2, ldsB, 0),     MM(0, 1), );
      PHASE(RD7, STG2(b2, b3, 2, ldsB, 8192),  MM(1, 0), );
      PHASE(   , STG2(a0, a1, 3, ldsA, 16384), MM(1, 1), WVM(2));
      a0 += 128; a1 += 128; a2 += 128; a3 += 128;
      b0 += 128; b1 += 128; b2 += 128; b3 += 128;
    }

    const bool hn = (rd + 1 < rounds);
    int ntr, ntc;
    mapTile(rd + 1, ntr, ntc);
    const int nrow0 = ntr << 8, ncol0 = ntc << 8;
    const bf16* na0 = A + (size_t)(nrow0 + srow) * KP + scol;
    const bf16* na1 = na0 + (size_t)64 * KP;
    const bf16* na2 = na0 + (size_t)128 * KP;
    const bf16* na3 = na0 + (size_t)192 * KP;
    const bf16* nb0 = B + (size_t)(ncol0 + srow) * KP + scol;
    const bf16* nb1 = nb0 + (size_t)64 * KP;
    const bf16* nb2 = nb0 + (size_t)128 * KP;
    const bf16* nb3 = nb0 + (size_t)192 * KP;

    PHASE(RD1, STG2(a2, a3, 1, ldsA, 24576), MM(0, 0), );
    PHASE(RD2, STG2(b0, b1, 1, ldsB, 16384), MM(0, 1), );
    PHASE(RD3, STG2(b2, b3, 1, ldsB, 24576), MM(1, 0), );
    PHASE(   , if (hn) { STG2(na0, na1, 0, ldsA, 0); },    MM(1, 1),
           if (hn) { WVM(2); } else { WVM(0); });
    PHASE(RD5, if (hn) { STG2(na2, na3, 0, ldsA, 8192); }, MM(0, 0), );
    PHASE(RD6, if (hn) { STG2(nb0, nb1, 0, ldsB, 0); },    MM(0, 1), );
    PHASE(RD7, if (hn) { STG2(nb2, nb3, 0, ldsB, 8192); }, MM(1, 0), );
    PHASE(   , if (hn) { STG2(na0, na1, 1, ldsA, 16384); }, MM(1, 1),
           if (hn) { WVM(2); } else { WVM(0); });

    // epilogue — C/D layout (verified): col = lane&15, row = (lane>>4)*4 + j
#pragma unroll
    for (int m = 0; m < 8; ++m) {
#pragma unroll
      for (int n = 0; n < 4; ++n) {
        const int r = row0 + wm * 128 + m * 16 + fq * 4;
        const int c = col0 + wn * 64 + n * 16 + fr;
#pragma unroll
        for (int j = 0; j < 4; ++j) {
          if (EPI == 1)
            Cf[(size_t)(r + j) * NP + c] = acc[m][n][j] + bias;
          else
            Cb[(size_t)(r + j) * NP + c] = (bf16)acc[m][n][j];
        }
      }
    }

    a0 = na0; a1 = na1; a2 = na2; a3 = na3;
    b0 = nb0; b1 = nb1; b2 = nb2; b3 = nb3;
    row0 = nrow0; col0 = ncol0;
  }
#undef STG2
#undef LDA4
#undef LDB2
#undef MM
#undef PHASE
#undef RD1
#undef RD2
#undef RD3
#undef RD5
#undef RD6
#undef RD7
}

// ---------------------------------------------------------------------------
// GEMM1 kernel: R14-verified 128x128 kk-half kernel (absmax 0.5, 0 bank
// conflicts, 2 blocks/CU). 512 tiles -> all 256 CUs in ONE round.
// ---------------------------------------------------------------------------
template <int EPI, int NP>
__global__ __launch_bounds__(512, 4)
void gemm128k(const bf16* __restrict__ A, const bf16* __restrict__ B,
              bf16* __restrict__ Cb, float* __restrict__ Cf,
              const float* __restrict__ bias_p, int M) {
  constexpr int KP = 1024;
  constexpr int NT = KP / 64;
  const int tid  = threadIdx.x;
  const int lane = tid & 63, wave = tid >> 6;
  const int wm = wave >> 1, wn = wave & 1;      // 4 x 2 waves
  const int fr = lane & 15, fq = lane >> 4;
  const int laneb = (fr >> 1) * 128 + ((((fr & 1) * 4 + fq) ^ ((fr >> 1) & 7)) << 4);

  const int bid = blockIdx.x;
  constexpr int gx = NP >> 7;
  const int nTiles = (M >> 7) * gx;
  int tr, tc;
  {
    const int swz = (bid & 7) * (nTiles >> 3) + (bid >> 3);
    tr = swz / gx; tc = swz % gx;
  }
  const int row0 = tr << 7, col0 = tc << 7;

  const int gsw  = (tid & 7) ^ ((tid >> 3) & 7);
  const int srow = 2 * (tid >> 3) + (gsw >> 2);
  const int chnk = gsw & 3;
  const bf16* Agl = A + (size_t)(row0 + srow) * KP + chnk * 8;
  const bf16* Bgl = B + (size_t)(col0 + srow) * KP + chnk * 8;

#define STG1(gp, base_off, t, kk)                                            \
  GLD_LDS((gp) + (size_t)(t) * 64 + (kk) * 32,                               \
          lds + (base_off) + ((t) & 1) * 16384 + (kk) * 8192 + wave * 1024)

  const char* Ab = lds + wm * 2048 + laneb;
  const char* Bb = lds + 32768 + wn * 4096 + laneb;

  f32x4  acc[2][4] = {};
  bf16x8 af[2], bg[4];

#define LDA(kk, p)                                                           \
  do {                                                                       \
    _Pragma("unroll") for (int m_ = 0; m_ < 2; ++m_)                         \
      af[m_] = *(const bf16x8*)(Ab + (p) * 16384 + (kk) * 8192 + m_ * 1024); \
  } while (0)

#define LDBH(np, kk, p)                                                      \
  do {                                                                       \
    _Pragma("unroll") for (int n_ = 0; n_ < 2; ++n_)                         \
      bg[(np) * 2 + n_] = *(const bf16x8*)(Bb + (p) * 16384 + (kk) * 8192 +  \
                                           ((np) * 2 + n_) * 1024);          \
  } while (0)

#define MM(np)                                                               \
  do {                                                                       \
    _Pragma("unroll") for (int m_ = 0; m_ < 2; ++m_)                         \
      _Pragma("unroll") for (int n_ = 0; n_ < 2; ++n_)                       \
        acc[m_][(np) * 2 + n_] = __builtin_amdgcn_mfma_f32_16x16x32_bf16(    \
            af[m_], bg[(np) * 2 + n_], acc[m_][(np) * 2 + n_], 0, 0, 0);     \
  } while (0)

  STG1(Agl, 0, 0, 0); STG1(Bgl, 32768, 0, 0);
  STG1(Agl, 0, 0, 1); STG1(Bgl, 32768, 0, 1);
  WVM(2); SB();

  for (int T = 0; T < NT; ++T) {
    const int p = T & 1;
    const bool st = (T + 1 < NT);
    LDA(0, p); LDBH(0, 0, p);
    if (st) STG1(Agl, 0, T + 1, 0);
    PRIO1(); MM(0); PRIO0();
    LDBH(1, 0, p);
    if (st) STG1(Bgl, 32768, T + 1, 0);
    PRIO1(); MM(1); PRIO0();
    if (st) { WVM(2); } else { WVM(0); }
    SB();
    LDA(1, p); LDBH(0, 1, p);
    if (st) STG1(Agl, 0, T + 1, 1);
    PRIO1(); MM(0); PRIO0();
    LDBH(1, 1, p);
    if (st) STG1(Bgl, 32768, T + 1, 1);
    PRIO1(); MM(1); PRIO0();
    if (st) { WVM(2); } else { WVM(0); }
    SB();
  }

  const float bias = (EPI == 1) ? bias_p[0] : 0.0f;
#pragma unroll
  for (int m = 0; m < 2; ++m) {
#pragma unroll
    for (int n = 0; n < 4; ++n) {
      const int r = row0 + wm * 32 + m * 16 + fq * 4;
      const int c = col0 + wn * 64 + n * 16 + fr;
#pragma unroll
      for (int j = 0; j < 4; ++j) {
        if (EPI == 1)
          Cf[(size_t)(r + j) * NP + c] = acc[m][n][j] + bias;
        else
          Cb[(size_t)(r + j) * NP + c] = (bf16)acc[m][n][j];
      }
    }
  }
#undef STG1
#undef LDA
#undef LDBH
#undef MM
}

// ---------------------------------------------------------------------------
// prep: fused X->bf16 cast (blocks [0,8192)) + W transpose+cast
// ---------------------------------------------------------------------------
__global__ void prep(const float* __restrict__ X, bf16* __restrict__ Xb,
                     const float* __restrict__ W, bf16* __restrict__ Wt) {
  __shared__ float s[32][33];
  const int bid = blockIdx.x;
  if (bid < 8192) {
    const int i = bid * 256 + threadIdx.x;
    const float4 v = ((const float4*)X)[i];
    bf16x4 o;
    o[0] = (bf16)v.x; o[1] = (bf16)v.y; o[2] = (bf16)v.z; o[3] = (bf16)v.w;
    ((bf16x4*)Xb)[i] = o;
  } else {
    const int b2 = bid - 8192;
    const int tx = threadIdx.x & 31;
    const int ty = threadIdx.x >> 5;
    const int n0 = (b2 & 31) * 32;
    const int k0 = (b2 >> 5) * 32;
#pragma unroll
    for (int p = 0; p < 4; ++p)
      s[ty + p * 8][tx] = W[(size_t)(k0 + ty + p * 8) * 1024 + n0 + tx];
    __syncthreads();
#pragma unroll
    for (int p = 0; p < 4; ++p)
      Wt[(size_t)(n0 + ty + p * 8) * 1024 + k0 + tx] = (bf16)s[tx][ty + p * 8];
  }
}

extern "C" void kernel_launch(void* const* d_in, const int* in_sizes, int n_in,
                              void* d_out, int out_size, void* d_ws, size_t ws_size,
                              hipStream_t stream) {
  const float* X = (const float*)d_in[0];   // (8192, 1024)
  const float* W = (const float*)d_in[1];   // (1024, 1024)
  const float* b = (const float*)d_in[2];   // (1,)
  float* out = (float*)d_out;               // (8192, 8192)

  const int Nn = 8192;
  char* ws = (char*)d_ws;
  bf16* Xb  = (bf16*)(ws);
  bf16* XWb = (bf16*)(ws + (size_t)16 * 1024 * 1024);
  bf16* Wt  = (bf16*)(ws + (size_t)32 * 1024 * 1024);

  // X->bf16 and W->Wt (fused)
  prep<<<9216, 256, 0, stream>>>(X, Xb, W, Wt);
  // GEMM1: XW = Xb * Wt^T  (8192x1024) -> bf16; 512 blocks = all CUs, 1 round
  gemm128k<0, 1024><<<512, 512, 65536, stream>>>(Xb, Wt, XWb, nullptr, nullptr,
                                                 Nn);
  // GEMM2: out = XWb * Xb^T + b  (8192x8192) fp32; 256 persistent blocks x 4
  gemm256<1, 8192><<<256, 512, 131072, stream>>>(XWb, Xb, nullptr, out, b, Nn);
}

// Round 19
// 178.696 us; speedup vs baseline: 1.2282x; 1.0198x over previous
//
#include <hip/hip_runtime.h>
#include <hip/hip_bf16.h>

typedef __bf16 bf16;
typedef __bf16 bf16x8 __attribute__((ext_vector_type(8)));
typedef __bf16 bf16x4 __attribute__((ext_vector_type(4)));
typedef float  f32x4  __attribute__((ext_vector_type(4)));

#define GLD_LDS(g, l)                                                        \
  __builtin_amdgcn_global_load_lds(                                          \
      (const __attribute__((address_space(1))) void*)(g),                    \
      (__attribute__((address_space(3))) void*)(l), 16, 0, 0)

#define SB()    __builtin_amdgcn_s_barrier()
#define WVM(n)  asm volatile("s_waitcnt vmcnt(" #n ")" ::: "memory")
#define PRIO1() __builtin_amdgcn_s_setprio(1)
#define PRIO0() __builtin_amdgcn_s_setprio(0)

// single TU-wide dynamic LDS symbol (char: both kernels cast as needed)
extern __shared__ char lds[];

// ---------------------------------------------------------------------------
// GEMM2 kernel: R12/R18 persistent 256x256 8-phase, SINGLE-BARRIER phases.
// Change vs R18 (one deleted SB per phase): PHASE = {reads; stage; MFMA;
// gate; SB}. The removed pre-MFMA barrier was redundant:
//  (i) stage-vs-read: region R's last readers consumed R in MFMAs that
//      completed before their phase's closing SB, >=2 barriers before any
//      stage targets R (ledger margins unchanged);
//  (ii) read-vs-stage residency: carried by per-wave counted WVM(2) + the
//      CLOSING SB (each wave drains its own stage loads; collectively the
//      tile is resident before any wave reads it) — gate+SB retained;
//  (iii) in-wave read->MFMA: compiler-inserted lgkm waits.
// Mechanism targeted: the double barrier forced sub-phase lockstep (MFMA
// pipe idle during read region and vice versa) = measured 37% MfmaUtil.
// Single barrier permits intra-phase slippage: one wave's MFMA overlaps
// another's ds_read/stage issue. Max skew still <=1 phase (closing SB).
// Ledger (verified): ph1 T+1.Ah1 | ph2 T+1.Bh0 | ph3 T+1.Bh1 | ph4 T+2.Ah0
// +WVM2 | ph5 T+2.Ah1 | ph6 T+2.Bh0 | ph7 T+2.Bh1 | ph8 T+3.Ah0 +WVM2.
// LDS 128K: A dbuf @0, B dbuf @65536; XOR swizzle byte bits4-6 ^= row&7 on
// reads, staging pre-swizzles the global k-chunk (rule #21 both-sides).
// ---------------------------------------------------------------------------
template <int EPI, int NP>
__global__ __launch_bounds__(512, 2)
void gemm256(const bf16* __restrict__ A, const bf16* __restrict__ B,
             bf16* __restrict__ Cb, float* __restrict__ Cf,
             const float* __restrict__ bias_p, int M) {
  constexpr int KP = 1024;
  constexpr int NT = KP / 64;            // 16 K-tiles
  bf16* ldsh = (bf16*)lds;
  const int tid  = threadIdx.x;
  const int lane = tid & 63, wave = tid >> 6;
  const int wm = wave >> 2, wn = wave & 3;       // 2 x 4 waves
  const int fr = lane & 15, fq = lane >> 4;
  const int xm = (fr & 7) << 4;
  const int kx0 = (fq * 16) ^ xm;
  const int kx1 = (fq * 16 + 64) ^ xm;

  const int nwg = gridDim.x;
  const int bid = blockIdx.x;
  constexpr int gx = NP >> 8;
  const int nTiles = (M >> 8) * gx;
  const int rounds = nTiles / nwg;

  const int srow = wave * 8 + (lane >> 3);
  const int scol = ((lane & 7) ^ (lane >> 3)) * 8;

  bf16* ldsA = ldsh + wave * 512;
  bf16* ldsB = ldsh + 32768 + wave * 512;
  const char* ldsc = (const char*)ldsh;
  const char* Ab0 = ldsc + wm * 16384 + fr * 128 + kx0;
  const char* Ab1 = ldsc + wm * 16384 + fr * 128 + kx1;
  const char* Bb0 = ldsc + 65536 + wn * 8192 + fr * 128 + kx0;
  const char* Bb1 = ldsc + 65536 + wn * 8192 + fr * 128 + kx1;

  const float bias = (EPI == 1) ? bias_p[0] : 0.0f;

#define STG2(p0, p1, trel, base, off)                                        \
  do {                                                                       \
    GLD_LDS((p0) + (trel) * 64, (base) + (off));                             \
    GLD_LDS((p1) + (trel) * 64, (base) + (off) + 4096);                      \
  } while (0)

#define LDA4(mg, kk, p)                                                      \
  do {                                                                       \
    _Pragma("unroll") for (int m_ = 0; m_ < 4; ++m_)                         \
      af[m_][kk] = *(const bf16x8*)(Ab##kk + (p) * 32768 +                   \
                                    ((mg) * 4 + m_) * 2048);                 \
  } while (0)

#define LDB2(np, kk, p)                                                      \
  do {                                                                       \
    _Pragma("unroll") for (int n_ = 0; n_ < 2; ++n_)                         \
      bg[(np) * 2 + n_][kk] = *(const bf16x8*)(Bb##kk + (p) * 32768 +        \
                                               ((np) * 2 + n_) * 2048);      \
  } while (0)

#define MM(mg, np)                                                           \
  do {                                                                       \
    _Pragma("unroll") for (int kk_ = 0; kk_ < 2; ++kk_)                      \
      _Pragma("unroll") for (int m_ = 0; m_ < 4; ++m_)                       \
        _Pragma("unroll") for (int n_ = 0; n_ < 2; ++n_)                     \
          acc[(mg) * 4 + m_][(np) * 2 + n_] =                                \
              __builtin_amdgcn_mfma_f32_16x16x32_bf16(                       \
                  af[m_][kk_], bg[(np) * 2 + n_][kk_],                       \
                  acc[(mg) * 4 + m_][(np) * 2 + n_], 0, 0, 0);               \
  } while (0)

// SINGLE-BARRIER phase: reads/stage issue, MFMA consumes (in-wave deps),
// counted gate, one closing barrier.
#define PHASE(RDS, STAGE, MMC, GATE)                                         \
  do { RDS; STAGE; PRIO1(); MMC; PRIO0(); GATE; SB(); } while (0)

#define RD1 do { LDB2(0,0,0); LDA4(0,0,0); LDB2(0,1,0); LDA4(0,1,0); } while(0)
#define RD2 do { LDB2(1,0,0); LDB2(1,1,0); } while(0)
#define RD3 do { LDA4(1,0,0); LDA4(1,1,0); } while(0)
#define RD5 do { LDB2(0,0,1); LDA4(0,0,1); LDB2(0,1,1); LDA4(0,1,1); } while(0)
#define RD6 do { LDB2(1,0,1); LDB2(1,1,1); } while(0)
#define RD7 do { LDA4(1,0,1); LDA4(1,1,1); } while(0)

  auto mapTile = [&](int rd, int& tr, int& tc) {
    if (NP == 8192 && nwg == 256 && (M >> 8) == 32) {
      const int xcd = bid & 7, pos = bid >> 3;
      tr = (rd >> 1) * 16 + (xcd >> 1) * 4 + (pos >> 3);
      tc = (rd & 1) * 16 + (xcd & 1) * 8 + (pos & 7);
    } else {
      const int li = rd * nwg + bid;
      const int swz = (li & 7) * (nTiles >> 3) + (li >> 3);
      tr = li < nTiles ? swz / gx : 0; tc = li < nTiles ? swz % gx : 0;
    }
  };

  int tr, tc;
  mapTile(0, tr, tc);
  int row0 = tr << 8, col0 = tc << 8;

  const bf16* a0 = A + (size_t)(row0 + srow) * KP + scol;
  const bf16* a1 = a0 + (size_t)64 * KP;
  const bf16* a2 = a0 + (size_t)128 * KP;
  const bf16* a3 = a0 + (size_t)192 * KP;
  const bf16* b0 = B + (size_t)(col0 + srow) * KP + scol;
  const bf16* b1 = b0 + (size_t)64 * KP;
  const bf16* b2 = b0 + (size_t)128 * KP;
  const bf16* b3 = b0 + (size_t)192 * KP;

  STG2(a0, a1, 0, ldsA, 0);
  STG2(a2, a3, 0, ldsA, 8192);
  STG2(b0, b1, 0, ldsB, 0);
  STG2(b2, b3, 0, ldsB, 8192);
  STG2(a0, a1, 1, ldsA, 16384);

  for (int rd = 0; rd < rounds; ++rd) {
    if (rd == 0) { WVM(2); } else { WVM(63); }
    SB();

    f32x4  acc[8][4] = {};
    bf16x8 af[4][2];
    bf16x8 bg[4][2];

#pragma unroll 1
    for (int it = 0; it < NT / 2 - 1; ++it) {
      PHASE(RD1, STG2(a2, a3, 1, ldsA, 24576), MM(0, 0), );
      PHASE(RD2, STG2(b0, b1, 1, ldsB, 16384), MM(0, 1), );
      PHASE(RD3, STG2(b2, b3, 1, ldsB, 24576), MM(1, 0), );
      PHASE(   , STG2(a0, a1, 2, ldsA, 0),     MM(1, 1), WVM(2));
      PHASE(RD5, STG2(a2, a3, 2, ldsA, 8192),  MM(0, 0), );
      PHASE(RD6, STG2(b0, b1, 2, ldsB, 0),     MM(0, 1), );
      PHASE(RD7, STG2(b2, b3, 2, ldsB, 8192),  MM(1, 0), );
      PHASE(   , STG2(a0, a1, 3, ldsA, 16384), MM(1, 1), WVM(2));
      a0 += 128; a1 += 128; a2 += 128; a3 += 128;
      b0 += 128; b1 += 128; b2 += 128; b3 += 128;
    }

    const bool hn = (rd + 1 < rounds);
    int ntr, ntc;
    mapTile(rd + 1, ntr, ntc);
    const int nrow0 = ntr << 8, ncol0 = ntc << 8;
    const bf16* na0 = A + (size_t)(nrow0 + srow) * KP + scol;
    const bf16* na1 = na0 + (size_t)64 * KP;
    const bf16* na2 = na0 + (size_t)128 * KP;
    const bf16* na3 = na0 + (size_t)192 * KP;
    const bf16* nb0 = B + (size_t)(ncol0 + srow) * KP + scol;
    const bf16* nb1 = nb0 + (size_t)64 * KP;
    const bf16* nb2 = nb0 + (size_t)128 * KP;
    const bf16* nb3 = nb0 + (size_t)192 * KP;

    PHASE(RD1, STG2(a2, a3, 1, ldsA, 24576), MM(0, 0), );
    PHASE(RD2, STG2(b0, b1, 1, ldsB, 16384), MM(0, 1), );
    PHASE(RD3, STG2(b2, b3, 1, ldsB, 24576), MM(1, 0), );
    PHASE(   , if (hn) { STG2(na0, na1, 0, ldsA, 0); },    MM(1, 1),
           if (hn) { WVM(2); } else { WVM(0); });
    PHASE(RD5, if (hn) { STG2(na2, na3, 0, ldsA, 8192); }, MM(0, 0), );
    PHASE(RD6, if (hn) { STG2(nb0, nb1, 0, ldsB, 0); },    MM(0, 1), );
    PHASE(RD7, if (hn) { STG2(nb2, nb3, 0, ldsB, 8192); }, MM(1, 0), );
    PHASE(   , if (hn) { STG2(na0, na1, 1, ldsA, 16384); }, MM(1, 1),
           if (hn) { WVM(2); } else { WVM(0); });

    // epilogue — C/D layout (verified): col = lane&15, row = (lane>>4)*4 + j
#pragma unroll
    for (int m = 0; m < 8; ++m) {
#pragma unroll
      for (int n = 0; n < 4; ++n) {
        const int r = row0 + wm * 128 + m * 16 + fq * 4;
        const int c = col0 + wn * 64 + n * 16 + fr;
#pragma unroll
        for (int j = 0; j < 4; ++j) {
          if (EPI == 1)
            Cf[(size_t)(r + j) * NP + c] = acc[m][n][j] + bias;
          else
            Cb[(size_t)(r + j) * NP + c] = (bf16)acc[m][n][j];
        }
      }
    }

    a0 = na0; a1 = na1; a2 = na2; a3 = na3;
    b0 = nb0; b1 = nb1; b2 = nb2; b3 = nb3;
    row0 = nrow0; col0 = ncol0;
  }
#undef STG2
#undef LDA4
#undef LDB2
#undef MM
#undef PHASE
#undef RD1
#undef RD2
#undef RD3
#undef RD5
#undef RD6
#undef RD7
}

// ---------------------------------------------------------------------------
// GEMM1 kernel: R14-verified 128x128 kk-half kernel (absmax 0.5, 0 bank
// conflicts, 2 blocks/CU). 512 tiles -> all 256 CUs in ONE round.
// ---------------------------------------------------------------------------
template <int EPI, int NP>
__global__ __launch_bounds__(512, 4)
void gemm128k(const bf16* __restrict__ A, const bf16* __restrict__ B,
              bf16* __restrict__ Cb, float* __restrict__ Cf,
              const float* __restrict__ bias_p, int M) {
  constexpr int KP = 1024;
  constexpr int NT = KP / 64;
  const int tid  = threadIdx.x;
  const int lane = tid & 63, wave = tid >> 6;
  const int wm = wave >> 1, wn = wave & 1;      // 4 x 2 waves
  const int fr = lane & 15, fq = lane >> 4;
  const int laneb = (fr >> 1) * 128 + ((((fr & 1) * 4 + fq) ^ ((fr >> 1) & 7)) << 4);

  const int bid = blockIdx.x;
  constexpr int gx = NP >> 7;
  const int nTiles = (M >> 7) * gx;
  int tr, tc;
  {
    const int swz = (bid & 7) * (nTiles >> 3) + (bid >> 3);
    tr = swz / gx; tc = swz % gx;
  }
  const int row0 = tr << 7, col0 = tc << 7;

  const int gsw  = (tid & 7) ^ ((tid >> 3) & 7);
  const int srow = 2 * (tid >> 3) + (gsw >> 2);
  const int chnk = gsw & 3;
  const bf16* Agl = A + (size_t)(row0 + srow) * KP + chnk * 8;
  const bf16* Bgl = B + (size_t)(col0 + srow) * KP + chnk * 8;

#define STG1(gp, base_off, t, kk)                                            \
  GLD_LDS((gp) + (size_t)(t) * 64 + (kk) * 32,                               \
          lds + (base_off) + ((t) & 1) * 16384 + (kk) * 8192 + wave * 1024)

  const char* Ab = lds + wm * 2048 + laneb;
  const char* Bb = lds + 32768 + wn * 4096 + laneb;

  f32x4  acc[2][4] = {};
  bf16x8 af[2], bg[4];

#define LDA(kk, p)                                                           \
  do {                                                                       \
    _Pragma("unroll") for (int m_ = 0; m_ < 2; ++m_)                         \
      af[m_] = *(const bf16x8*)(Ab + (p) * 16384 + (kk) * 8192 + m_ * 1024); \
  } while (0)

#define LDBH(np, kk, p)                                                      \
  do {                                                                       \
    _Pragma("unroll") for (int n_ = 0; n_ < 2; ++n_)                         \
      bg[(np) * 2 + n_] = *(const bf16x8*)(Bb + (p) * 16384 + (kk) * 8192 +  \
                                           ((np) * 2 + n_) * 1024);          \
  } while (0)

#define MM(np)                                                               \
  do {                                                                       \
    _Pragma("unroll") for (int m_ = 0; m_ < 2; ++m_)                         \
      _Pragma("unroll") for (int n_ = 0; n_ < 2; ++n_)                       \
        acc[m_][(np) * 2 + n_] = __builtin_amdgcn_mfma_f32_16x16x32_bf16(    \
            af[m_], bg[(np) * 2 + n_], acc[m_][(np) * 2 + n_], 0, 0, 0);     \
  } while (0)

  STG1(Agl, 0, 0, 0); STG1(Bgl, 32768, 0, 0);
  STG1(Agl, 0, 0, 1); STG1(Bgl, 32768, 0, 1);
  WVM(2); SB();

  for (int T = 0; T < NT; ++T) {
    const int p = T & 1;
    const bool st = (T + 1 < NT);
    LDA(0, p); LDBH(0, 0, p);
    if (st) STG1(Agl, 0, T + 1, 0);
    PRIO1(); MM(0); PRIO0();
    LDBH(1, 0, p);
    if (st) STG1(Bgl, 32768, T + 1, 0);
    PRIO1(); MM(1); PRIO0();
    if (st) { WVM(2); } else { WVM(0); }
    SB();
    LDA(1, p); LDBH(0, 1, p);
    if (st) STG1(Agl, 0, T + 1, 1);
    PRIO1(); MM(0); PRIO0();
    LDBH(1, 1, p);
    if (st) STG1(Bgl, 32768, T + 1, 1);
    PRIO1(); MM(1); PRIO0();
    if (st) { WVM(2); } else { WVM(0); }
    SB();
  }

  const float bias = (EPI == 1) ? bias_p[0] : 0.0f;
#pragma unroll
  for (int m = 0; m < 2; ++m) {
#pragma unroll
    for (int n = 0; n < 4; ++n) {
      const int r = row0 + wm * 32 + m * 16 + fq * 4;
      const int c = col0 + wn * 64 + n * 16 + fr;
#pragma unroll
      for (int j = 0; j < 4; ++j) {
        if (EPI == 1)
          Cf[(size_t)(r + j) * NP + c] = acc[m][n][j] + bias;
        else
          Cb[(size_t)(r + j) * NP + c] = (bf16)acc[m][n][j];
      }
    }
  }
#undef STG1
#undef LDA
#undef LDBH
#undef MM
}

// ---------------------------------------------------------------------------
// prep: fused X->bf16 cast (blocks [0,8192)) + W transpose+cast
// ---------------------------------------------------------------------------
__global__ void prep(const float* __restrict__ X, bf16* __restrict__ Xb,
                     const float* __restrict__ W, bf16* __restrict__ Wt) {
  __shared__ float s[32][33];
  const int bid = blockIdx.x;
  if (bid < 8192) {
    const int i = bid * 256 + threadIdx.x;
    const float4 v = ((const float4*)X)[i];
    bf16x4 o;
    o[0] = (bf16)v.x; o[1] = (bf16)v.y; o[2] = (bf16)v.z; o[3] = (bf16)v.w;
    ((bf16x4*)Xb)[i] = o;
  } else {
    const int b2 = bid - 8192;
    const int tx = threadIdx.x & 31;
    const int ty = threadIdx.x >> 5;
    const int n0 = (b2 & 31) * 32;
    const int k0 = (b2 >> 5) * 32;
#pragma unroll
    for (int p = 0; p < 4; ++p)
      s[ty + p * 8][tx] = W[(size_t)(k0 + ty + p * 8) * 1024 + n0 + tx];
    __syncthreads();
#pragma unroll
    for (int p = 0; p < 4; ++p)
      Wt[(size_t)(n0 + ty + p * 8) * 1024 + k0 + tx] = (bf16)s[tx][ty + p * 8];
  }
}

extern "C" void kernel_launch(void* const* d_in, const int* in_sizes, int n_in,
                              void* d_out, int out_size, void* d_ws, size_t ws_size,
                              hipStream_t stream) {
  const float* X = (const float*)d_in[0];   // (8192, 1024)
  const float* W = (const float*)d_in[1];   // (1024, 1024)
  const float* b = (const float*)d_in[2];   // (1,)
  float* out = (float*)d_out;               // (8192, 8192)

  const int Nn = 8192;
  char* ws = (char*)d_ws;
  bf16* Xb  = (bf16*)(ws);
  bf16* XWb = (bf16*)(ws + (size_t)16 * 1024 * 1024);
  bf16* Wt  = (bf16*)(ws + (size_t)32 * 1024 * 1024);

  // X->bf16 and W->Wt (fused)
  prep<<<9216, 256, 0, stream>>>(X, Xb, W, Wt);
  // GEMM1: XW = Xb * Wt^T  (8192x1024) -> bf16; 512 blocks = all CUs, 1 round
  gemm128k<0, 1024><<<512, 512, 65536, stream>>>(Xb, Wt, XWb, nullptr, nullptr,
                                                 Nn);
  // GEMM2: out = XWb * Xb^T + b  (8192x8192) fp32; 256 persistent blocks x 4
  gemm256<1, 8192><<<256, 512, 131072, stream>>>(XWb, Xb, nullptr, out, b, Nn);
}